// Round 5
// baseline (673.651 us; speedup 1.0000x reference)
//
#include <hip/hip_runtime.h>
#include <math.h>

#define N_NODES 50000
#define N_EDGES 1600000
#define ETOT (N_EDGES + N_NODES)
#define HC 128
#define HEADS 4
#define HID 32
#define NEG_SLOPE 0.2f
#define NPB 32                               // nodes per bucket (aligned)
#define NBUCKETS ((N_NODES + NPB - 1) / NPB) // 1563
#define CHUNK 8192
#define NCHUNK ((ETOT + CHUNK - 1) / CHUNK)  // 202
#define LOG2E 1.4426950408889634f
#define NEGBIG (-1e30f)

// ---------------- CSR build ----------------

__global__ __launch_bounds__(256) void hist_kernel(const int* __restrict__ dstArr, int* __restrict__ deg) {
    int i = blockIdx.x * 256 + threadIdx.x;
    if (i >= ETOT) return;
    int d = (i < N_EDGES) ? dstArr[i] : (i - N_EDGES);
    atomicAdd(&deg[d], 1);
}

__global__ __launch_bounds__(1024) void scanA_kernel(const int* __restrict__ deg,
                                                     int* __restrict__ rowStart, int* __restrict__ blockSum) {
    __shared__ int buf[1024];
    int i = blockIdx.x * 1024 + threadIdx.x;
    int v = (i < N_NODES) ? deg[i] : 0;
    buf[threadIdx.x] = v;
    __syncthreads();
    for (int off = 1; off < 1024; off <<= 1) {
        int t = (threadIdx.x >= off) ? buf[threadIdx.x - off] : 0;
        __syncthreads();
        buf[threadIdx.x] += t;
        __syncthreads();
    }
    if (i < N_NODES) rowStart[i] = buf[threadIdx.x] - v;   // exclusive, pre-offset
    if (threadIdx.x == 1023) blockSum[blockIdx.x] = buf[1023];
}

__global__ void scanB_kernel(const int* __restrict__ blockSum, int* __restrict__ blockOff, int nb) {
    if (threadIdx.x == 0 && blockIdx.x == 0) {
        int acc = 0;
        for (int j = 0; j < nb; j++) { blockOff[j] = acc; acc += blockSum[j]; }
    }
}

__global__ __launch_bounds__(1024) void scanC_kernel(int* __restrict__ rowStart, const int* __restrict__ blockOff) {
    int i = blockIdx.x * 1024 + threadIdx.x;
    if (i < N_NODES) rowStart[i] += blockOff[blockIdx.x];
    if (i == 0) rowStart[N_NODES] = ETOT;   // sentinel
}

__global__ __launch_bounds__(256) void init_cursor_kernel(const int* __restrict__ rowStart, int* __restrict__ bucketCursor) {
    int b = blockIdx.x * 256 + threadIdx.x;
    if (b < NBUCKETS) bucketCursor[b] = rowStart[b * NPB];
}

// Pass 1: chunked counting-sort scatter to bucket granularity.
// One global atomic per (block,bucket). Edge packed src | (d<<16) (both < 2^16).
__global__ __launch_bounds__(256) void chunk_scatter_kernel(const int* __restrict__ srcArr, const int* __restrict__ dstArr,
                                                            int* __restrict__ bucketCursor, int* __restrict__ E) {
    __shared__ int hist[NBUCKETS];   // then reused as running cursor
    int c0 = blockIdx.x * CHUNK;
    int c1 = min(c0 + CHUNK, ETOT);
    for (int b = threadIdx.x; b < NBUCKETS; b += 256) hist[b] = 0;
    __syncthreads();

    int myP[CHUNK / 256];   // packed src | (d<<16)
    int cnt = 0;
    for (int i = c0 + threadIdx.x; i < c1; i += 256) {
        int s, d;
        if (i < N_EDGES) { s = srcArr[i]; d = dstArr[i]; }
        else             { s = i - N_EDGES; d = s; }
        myP[cnt] = s | (d << 16);
        cnt++;
        atomicAdd(&hist[d >> 5], 1);
    }
    __syncthreads();
    for (int b = threadIdx.x; b < NBUCKETS; b += 256) {
        int h = hist[b];
        hist[b] = (h > 0) ? atomicAdd(&bucketCursor[b], h) : 0;
    }
    __syncthreads();
    for (int k = 0; k < cnt; k++) {
        int pe = myP[k];
        int pos = atomicAdd(&hist[((unsigned)pe) >> 21], 1);   // bucket = d>>5 = pe>>21
        E[pos] = pe;
    }
}

// Pass 2: one block per bucket; emits BYTE offsets src*512 into srcOff
__global__ __launch_bounds__(256) void csr_scatter_kernel(const int* __restrict__ E, const int* __restrict__ rowStart,
                                                          int* __restrict__ srcOff) {
    __shared__ int lcur[NPB];
    int b = blockIdx.x;
    int n0 = b * NPB;
    int nend = min(n0 + NPB, N_NODES);
    if (threadIdx.x < nend - n0) lcur[threadIdx.x] = rowStart[n0 + threadIdx.x];
    __syncthreads();
    int e0 = rowStart[n0];
    int e1 = rowStart[nend];
    for (int i = e0 + threadIdx.x; i < e1; i += 256) {
        int pe = E[i];
        int pos = atomicAdd(&lcur[(pe >> 16) & (NPB - 1)], 1);
        srcOff[pos] = (pe & 0xFFFF) << 9;     // byte offset into XL (row = 512 B)
    }
}

// ---------------- GEMM: XL = x@Wl + bl, XR = x@Wr + br (shared A-tile) ----------------
// grid = (ceil(N/64), 2); blockIdx.y = 64-col tile. Each block computes BOTH
// the XL and XR output tiles, loading the A tile once.

__global__ __launch_bounds__(256) void gemm_kernel(const float* __restrict__ x,
    const float* __restrict__ Wl, const float* __restrict__ bl,
    const float* __restrict__ Wr, const float* __restrict__ br,
    float* __restrict__ XL, float* __restrict__ XR) {
    __shared__ float As[64][68];
    __shared__ float Bl[64][64];
    __shared__ float Br[64][64];
    int t = threadIdx.x;
    int rb = blockIdx.x * 64;
    int c0 = blockIdx.y * 64;
    int tx = t & 15, ty = t >> 4;
    float accl[4][4], accr[4][4];
#pragma unroll
    for (int i = 0; i < 4; i++)
#pragma unroll
        for (int j = 0; j < 4; j++) { accl[i][j] = 0.f; accr[i][j] = 0.f; }

    for (int kt = 0; kt < 2; kt++) {
#pragma unroll
        for (int it = 0; it < 4; it++) {
            int idx = it * 256 + t;
            int r = idx >> 4, f = idx & 15;
            int gr = rb + r;
            float4 v = make_float4(0.f, 0.f, 0.f, 0.f);
            if (gr < N_NODES) v = *reinterpret_cast<const float4*>(&x[gr * HC + kt * 64 + f * 4]);
            *reinterpret_cast<float4*>(&As[r][f * 4]) = v;
        }
#pragma unroll
        for (int it = 0; it < 4; it++) {
            int idx = it * 256 + t;
            int k = idx >> 4, f = idx & 15;
            *reinterpret_cast<float4*>(&Bl[k][f * 4]) =
                *reinterpret_cast<const float4*>(&Wl[(kt * 64 + k) * HC + c0 + f * 4]);
            *reinterpret_cast<float4*>(&Br[k][f * 4]) =
                *reinterpret_cast<const float4*>(&Wr[(kt * 64 + k) * HC + c0 + f * 4]);
        }
        __syncthreads();
#pragma unroll
        for (int k = 0; k < 64; k++) {
            float a0 = As[ty * 4 + 0][k];
            float a1 = As[ty * 4 + 1][k];
            float a2 = As[ty * 4 + 2][k];
            float a3 = As[ty * 4 + 3][k];
            float4 bv = *reinterpret_cast<const float4*>(&Bl[k][tx * 4]);
            float4 cv = *reinterpret_cast<const float4*>(&Br[k][tx * 4]);
            accl[0][0] += a0 * bv.x; accl[0][1] += a0 * bv.y; accl[0][2] += a0 * bv.z; accl[0][3] += a0 * bv.w;
            accl[1][0] += a1 * bv.x; accl[1][1] += a1 * bv.y; accl[1][2] += a1 * bv.z; accl[1][3] += a1 * bv.w;
            accl[2][0] += a2 * bv.x; accl[2][1] += a2 * bv.y; accl[2][2] += a2 * bv.z; accl[2][3] += a2 * bv.w;
            accl[3][0] += a3 * bv.x; accl[3][1] += a3 * bv.y; accl[3][2] += a3 * bv.z; accl[3][3] += a3 * bv.w;
            accr[0][0] += a0 * cv.x; accr[0][1] += a0 * cv.y; accr[0][2] += a0 * cv.z; accr[0][3] += a0 * cv.w;
            accr[1][0] += a1 * cv.x; accr[1][1] += a1 * cv.y; accr[1][2] += a1 * cv.z; accr[1][3] += a1 * cv.w;
            accr[2][0] += a2 * cv.x; accr[2][1] += a2 * cv.y; accr[2][2] += a2 * cv.z; accr[2][3] += a2 * cv.w;
            accr[3][0] += a3 * cv.x; accr[3][1] += a3 * cv.y; accr[3][2] += a3 * cv.z; accr[3][3] += a3 * cv.w;
        }
        __syncthreads();
    }
    float4 bbl = *reinterpret_cast<const float4*>(&bl[c0 + tx * 4]);
    float4 bbr = *reinterpret_cast<const float4*>(&br[c0 + tx * 4]);
#pragma unroll
    for (int i = 0; i < 4; i++) {
        int gr = rb + ty * 4 + i;
        if (gr < N_NODES) {
            float4 o;
            o.x = accl[i][0] + bbl.x; o.y = accl[i][1] + bbl.y;
            o.z = accl[i][2] + bbl.z; o.w = accl[i][3] + bbl.w;
            *reinterpret_cast<float4*>(&XL[gr * HC + c0 + tx * 4]) = o;
            o.x = accr[i][0] + bbr.x; o.y = accr[i][1] + bbr.y;
            o.z = accr[i][2] + bbr.z; o.w = accr[i][3] + bbr.w;
            *reinterpret_cast<float4*>(&XR[gr * HC + c0 + tx * 4]) = o;
        }
    }
}

// ---------------- Fused GAT: 2 edges/wave, float4 lanes ----------------
// Lane l: half = l>>5 picks edge p or p+1; cb = l&31 covers channels [4cb,4cb+4);
// head = cb>>3 (8-lane head groups). Scores in log2 domain (att pre-scaled).

__device__ __forceinline__ float score4(float4 xl, float4 xr, float4 a) {
    float hx = xl.x + xr.x, hy = xl.y + xr.y, hz = xl.z + xr.z, hw = xl.w + xr.w;
    hx = fmaxf(hx, NEG_SLOPE * hx);
    hy = fmaxf(hy, NEG_SLOPE * hy);
    hz = fmaxf(hz, NEG_SLOPE * hz);
    hw = fmaxf(hw, NEG_SLOPE * hw);
    float c = ((a.x * hx + a.y * hy) + (a.z * hz + a.w * hw));
    c += __shfl_xor(c, 1);
    c += __shfl_xor(c, 2);
    c += __shfl_xor(c, 4);     // 8-lane head group now holds e_h * log2e
    return c;
}

__device__ __forceinline__ void upd4(float c, float4 xl, float& m, float& z, float4& acc) {
    if (__any(c > m)) {
        float nm = fmaxf(m, c);
        float s = exp2f(m - nm);
        float w = exp2f(c - nm);
        z = z * s + w;
        acc.x = acc.x * s + w * xl.x;
        acc.y = acc.y * s + w * xl.y;
        acc.z = acc.z * s + w * xl.z;
        acc.w = acc.w * s + w * xl.w;
        m = nm;
    } else {
        float w = exp2f(c - m);
        z += w;
        acc.x += w * xl.x;
        acc.y += w * xl.y;
        acc.z += w * xl.z;
        acc.w += w * xl.w;
    }
}

__global__ __launch_bounds__(256) void gat_fused_kernel(const float* __restrict__ XL,
    const float* __restrict__ XR, const float* __restrict__ att,
    const int* __restrict__ rowStart, const int* __restrict__ srcOff,
    const float* __restrict__ bvec, float* __restrict__ out, int applyElu) {
    int wv = threadIdx.x >> 6;
    int l = threadIdx.x & 63;
    int half = l >> 5;
    int cb = l & 31;
    int n = blockIdx.x * 4 + wv;
    if (n >= N_NODES) return;
    int s0 = rowStart[n], s1 = rowStart[n + 1];

    float4 xr4 = *reinterpret_cast<const float4*>(&XR[n * HC + 4 * cb]);
    float4 a4  = *reinterpret_cast<const float4*>(&att[4 * cb]);
    a4.x *= LOG2E; a4.y *= LOG2E; a4.z *= LOG2E; a4.w *= LOG2E;
    const char* XLb = reinterpret_cast<const char*>(XL);
    int lo = 16 * cb;

    float m = NEGBIG, z = 0.f;
    float4 acc = make_float4(0.f, 0.f, 0.f, 0.f);

    int p = s0;
    for (; p + 2 <= s1; p += 2) {
        int o = srcOff[p + half];               // half 0 -> p, half 1 -> p+1
        float4 xl4 = *reinterpret_cast<const float4*>(XLb + (size_t)(o + lo));
        float c = score4(xl4, xr4, a4);
        upd4(c, xl4, m, z, acc);
    }
    if (p < s1) {                               // odd tail: half 1 masked
        int o = srcOff[p];
        float4 xl4 = *reinterpret_cast<const float4*>(XLb + (size_t)(o + lo));
        float c = score4(xl4, xr4, a4);
        if (half) c = NEGBIG;                   // finite poison: no NaN, killed at combine
        upd4(c, xl4, m, z, acc);
    }

    // merge the two half-wave softmax states (exact rescale combine)
    float mo = __shfl_xor(m, 32);
    float zo = __shfl_xor(z, 32);
    float aox = __shfl_xor(acc.x, 32);
    float aoy = __shfl_xor(acc.y, 32);
    float aoz = __shfl_xor(acc.z, 32);
    float aow = __shfl_xor(acc.w, 32);
    float nm = fmaxf(m, mo);
    float s  = exp2f(m - nm);
    float so = exp2f(mo - nm);
    z = z * s + zo * so;
    acc.x = acc.x * s + aox * so;
    acc.y = acc.y * s + aoy * so;
    acc.z = acc.z * s + aoz * so;
    acc.w = acc.w * s + aow * so;

    if (half == 0) {
        float zinv = 1.f / z;
        float4 b4 = *reinterpret_cast<const float4*>(&bvec[4 * cb]);
        float4 o4;
        o4.x = acc.x * zinv + b4.x;
        o4.y = acc.y * zinv + b4.y;
        o4.z = acc.z * zinv + b4.z;
        o4.w = acc.w * zinv + b4.w;
        if (applyElu) {
            o4.x = o4.x > 0.f ? o4.x : (__expf(o4.x) - 1.f);
            o4.y = o4.y > 0.f ? o4.y : (__expf(o4.y) - 1.f);
            o4.z = o4.z > 0.f ? o4.z : (__expf(o4.z) - 1.f);
            o4.w = o4.w > 0.f ? o4.w : (__expf(o4.w) - 1.f);
        }
        *reinterpret_cast<float4*>(&out[n * HC + 4 * cb]) = o4;
    }
}

// ---------------- launch ----------------

extern "C" void kernel_launch(void* const* d_in, const int* in_sizes, int n_in,
                              void* d_out, int out_size, void* d_ws, size_t ws_size,
                              hipStream_t stream) {
    const float* x = (const float*)d_in[0];
    const int* ei = (const int*)d_in[1];
    const int* srcArr = ei;
    const int* dstArr = ei + N_EDGES;

    char* ws = (char*)d_ws;
    size_t off = 0;
    auto alloc = [&](size_t bytes) -> void* {
        void* p = ws + off;
        off = (off + bytes + 511) & ~(size_t)511;
        return p;
    };
    float* P       = (float*)alloc((size_t)N_NODES * HC * 4);
    float* XL      = (float*)alloc((size_t)N_NODES * HC * 4);
    float* XR      = (float*)alloc((size_t)N_NODES * HC * 4);
    int* deg       = (int*)alloc((size_t)N_NODES * 4);
    int* rowStart  = (int*)alloc((size_t)(N_NODES + 1) * 4);
    int* blockSum  = (int*)alloc(64 * 4);
    int* blockOff  = (int*)alloc(64 * 4);
    int* bucketCur = (int*)alloc((size_t)NBUCKETS * 4);
    int* E         = (int*)alloc((size_t)ETOT * 4);
    int* srcOff    = (int*)alloc((size_t)ETOT * 4);

    const int NSCAN = (N_NODES + 1023) / 1024;   // 49

    hipMemsetAsync(deg, 0, (size_t)N_NODES * 4, stream);
    hist_kernel<<<(ETOT + 255) / 256, 256, 0, stream>>>(dstArr, deg);
    scanA_kernel<<<NSCAN, 1024, 0, stream>>>(deg, rowStart, blockSum);
    scanB_kernel<<<1, 64, 0, stream>>>(blockSum, blockOff, NSCAN);
    scanC_kernel<<<NSCAN, 1024, 0, stream>>>(rowStart, blockOff);
    init_cursor_kernel<<<(NBUCKETS + 255) / 256, 256, 0, stream>>>(rowStart, bucketCur);
    chunk_scatter_kernel<<<NCHUNK, 256, 0, stream>>>(srcArr, dstArr, bucketCur, E);
    csr_scatter_kernel<<<NBUCKETS, 256, 0, stream>>>(E, rowStart, srcOff);

    for (int lyr = 0; lyr < 3; lyr++) {
        const float* xin = (lyr == 0) ? x : P;
        float* xout = (lyr == 2) ? (float*)d_out : P;
        const float* Wl  = (const float*)d_in[2 + 6 * lyr + 0];
        const float* bl  = (const float*)d_in[2 + 6 * lyr + 1];
        const float* Wr  = (const float*)d_in[2 + 6 * lyr + 2];
        const float* br  = (const float*)d_in[2 + 6 * lyr + 3];
        const float* att = (const float*)d_in[2 + 6 * lyr + 4];
        const float* bb  = (const float*)d_in[2 + 6 * lyr + 5];

        dim3 ggrid((N_NODES + 63) / 64, 2);
        gemm_kernel<<<ggrid, 256, 0, stream>>>(xin, Wl, bl, Wr, br, XL, XR);

        int nb = (N_NODES + 3) / 4;
        gat_fused_kernel<<<nb, 256, 0, stream>>>(XL, XR, att, rowStart, srcOff, bb, xout, lyr < 2 ? 1 : 0);
    }
}

// Round 6
// 620.121 us; speedup vs baseline: 1.0863x; 1.0863x over previous
//
#include <hip/hip_runtime.h>
#include <math.h>

#define N_NODES 50000
#define N_EDGES 1600000
#define ETOT (N_EDGES + N_NODES)
#define HC 128
#define HEADS 4
#define HID 32
#define NEG_SLOPE 0.2f
#define NPB 32                               // nodes per bucket (aligned)
#define NBUCKETS ((N_NODES + NPB - 1) / NPB) // 1563
#define CHUNK 8192
#define NCHUNK ((ETOT + CHUNK - 1) / CHUNK)  // 202
#define LOG2E 1.4426950408889634f
#define NEGBIG (-1e30f)

// ---------------- CSR build ----------------

__global__ __launch_bounds__(256) void hist_kernel(const int* __restrict__ dstArr, int* __restrict__ deg) {
    int i = blockIdx.x * 256 + threadIdx.x;
    if (i >= ETOT) return;
    int d = (i < N_EDGES) ? dstArr[i] : (i - N_EDGES);
    atomicAdd(&deg[d], 1);
}

__global__ __launch_bounds__(1024) void scanA_kernel(const int* __restrict__ deg,
                                                     int* __restrict__ rowStart, int* __restrict__ blockSum) {
    __shared__ int buf[1024];
    int i = blockIdx.x * 1024 + threadIdx.x;
    int v = (i < N_NODES) ? deg[i] : 0;
    buf[threadIdx.x] = v;
    __syncthreads();
    for (int off = 1; off < 1024; off <<= 1) {
        int t = (threadIdx.x >= off) ? buf[threadIdx.x - off] : 0;
        __syncthreads();
        buf[threadIdx.x] += t;
        __syncthreads();
    }
    if (i < N_NODES) rowStart[i] = buf[threadIdx.x] - v;   // exclusive, pre-offset
    if (threadIdx.x == 1023) blockSum[blockIdx.x] = buf[1023];
}

__global__ void scanB_kernel(const int* __restrict__ blockSum, int* __restrict__ blockOff, int nb) {
    if (threadIdx.x == 0 && blockIdx.x == 0) {
        int acc = 0;
        for (int j = 0; j < nb; j++) { blockOff[j] = acc; acc += blockSum[j]; }
    }
}

__global__ __launch_bounds__(1024) void scanC_kernel(int* __restrict__ rowStart, const int* __restrict__ blockOff) {
    int i = blockIdx.x * 1024 + threadIdx.x;
    if (i < N_NODES) rowStart[i] += blockOff[blockIdx.x];
    if (i == 0) rowStart[N_NODES] = ETOT;   // sentinel
}

__global__ __launch_bounds__(256) void init_cursor_kernel(const int* __restrict__ rowStart, int* __restrict__ bucketCursor) {
    int b = blockIdx.x * 256 + threadIdx.x;
    if (b < NBUCKETS) bucketCursor[b] = rowStart[b * NPB];
}

// Pass 1: chunked counting-sort scatter to bucket granularity.
__global__ __launch_bounds__(256) void chunk_scatter_kernel(const int* __restrict__ srcArr, const int* __restrict__ dstArr,
                                                            int* __restrict__ bucketCursor, int* __restrict__ E) {
    __shared__ int hist[NBUCKETS];   // then reused as running cursor
    int c0 = blockIdx.x * CHUNK;
    int c1 = min(c0 + CHUNK, ETOT);
    for (int b = threadIdx.x; b < NBUCKETS; b += 256) hist[b] = 0;
    __syncthreads();

    int myP[CHUNK / 256];   // packed src | (d<<16)
    int cnt = 0;
    for (int i = c0 + threadIdx.x; i < c1; i += 256) {
        int s, d;
        if (i < N_EDGES) { s = srcArr[i]; d = dstArr[i]; }
        else             { s = i - N_EDGES; d = s; }
        myP[cnt] = s | (d << 16);
        cnt++;
        atomicAdd(&hist[d >> 5], 1);
    }
    __syncthreads();
    for (int b = threadIdx.x; b < NBUCKETS; b += 256) {
        int h = hist[b];
        hist[b] = (h > 0) ? atomicAdd(&bucketCursor[b], h) : 0;
    }
    __syncthreads();
    for (int k = 0; k < cnt; k++) {
        int pe = myP[k];
        int pos = atomicAdd(&hist[((unsigned)pe) >> 21], 1);   // bucket = d>>5
        E[pos] = pe;
    }
}

// Pass 2: one block per bucket; emits BYTE offsets src*512 into srcOff
__global__ __launch_bounds__(256) void csr_scatter_kernel(const int* __restrict__ E, const int* __restrict__ rowStart,
                                                          int* __restrict__ srcOff) {
    __shared__ int lcur[NPB];
    int b = blockIdx.x;
    int n0 = b * NPB;
    int nend = min(n0 + NPB, N_NODES);
    if (threadIdx.x < nend - n0) lcur[threadIdx.x] = rowStart[n0 + threadIdx.x];
    __syncthreads();
    int e0 = rowStart[n0];
    int e1 = rowStart[nend];
    for (int i = e0 + threadIdx.x; i < e1; i += 256) {
        int pe = E[i];
        int pos = atomicAdd(&lcur[(pe >> 16) & (NPB - 1)], 1);
        srcOff[pos] = (pe & 0xFFFF) << 9;     // byte offset into XL (row = 512 B)
    }
}

// ---------------- GEMM: XL = x@Wl + bl, XR = x@Wr + br (shared A-tile) ----------------

__global__ __launch_bounds__(256) void gemm_kernel(const float* __restrict__ x,
    const float* __restrict__ Wl, const float* __restrict__ bl,
    const float* __restrict__ Wr, const float* __restrict__ br,
    float* __restrict__ XL, float* __restrict__ XR) {
    __shared__ float As[64][68];
    __shared__ float Bl[64][64];
    __shared__ float Br[64][64];
    int t = threadIdx.x;
    int rb = blockIdx.x * 64;
    int c0 = blockIdx.y * 64;
    int tx = t & 15, ty = t >> 4;
    float accl[4][4], accr[4][4];
#pragma unroll
    for (int i = 0; i < 4; i++)
#pragma unroll
        for (int j = 0; j < 4; j++) { accl[i][j] = 0.f; accr[i][j] = 0.f; }

    for (int kt = 0; kt < 2; kt++) {
#pragma unroll
        for (int it = 0; it < 4; it++) {
            int idx = it * 256 + t;
            int r = idx >> 4, f = idx & 15;
            int gr = rb + r;
            float4 v = make_float4(0.f, 0.f, 0.f, 0.f);
            if (gr < N_NODES) v = *reinterpret_cast<const float4*>(&x[gr * HC + kt * 64 + f * 4]);
            *reinterpret_cast<float4*>(&As[r][f * 4]) = v;
        }
#pragma unroll
        for (int it = 0; it < 4; it++) {
            int idx = it * 256 + t;
            int k = idx >> 4, f = idx & 15;
            *reinterpret_cast<float4*>(&Bl[k][f * 4]) =
                *reinterpret_cast<const float4*>(&Wl[(kt * 64 + k) * HC + c0 + f * 4]);
            *reinterpret_cast<float4*>(&Br[k][f * 4]) =
                *reinterpret_cast<const float4*>(&Wr[(kt * 64 + k) * HC + c0 + f * 4]);
        }
        __syncthreads();
#pragma unroll
        for (int k = 0; k < 64; k++) {
            float a0 = As[ty * 4 + 0][k];
            float a1 = As[ty * 4 + 1][k];
            float a2 = As[ty * 4 + 2][k];
            float a3 = As[ty * 4 + 3][k];
            float4 bv = *reinterpret_cast<const float4*>(&Bl[k][tx * 4]);
            float4 cv = *reinterpret_cast<const float4*>(&Br[k][tx * 4]);
            accl[0][0] += a0 * bv.x; accl[0][1] += a0 * bv.y; accl[0][2] += a0 * bv.z; accl[0][3] += a0 * bv.w;
            accl[1][0] += a1 * bv.x; accl[1][1] += a1 * bv.y; accl[1][2] += a1 * bv.z; accl[1][3] += a1 * bv.w;
            accl[2][0] += a2 * bv.x; accl[2][1] += a2 * bv.y; accl[2][2] += a2 * bv.z; accl[2][3] += a2 * bv.w;
            accl[3][0] += a3 * bv.x; accl[3][1] += a3 * bv.y; accl[3][2] += a3 * bv.z; accl[3][3] += a3 * bv.w;
            accr[0][0] += a0 * cv.x; accr[0][1] += a0 * cv.y; accr[0][2] += a0 * cv.z; accr[0][3] += a0 * cv.w;
            accr[1][0] += a1 * cv.x; accr[1][1] += a1 * cv.y; accr[1][2] += a1 * cv.z; accr[1][3] += a1 * cv.w;
            accr[2][0] += a2 * cv.x; accr[2][1] += a2 * cv.y; accr[2][2] += a2 * cv.z; accr[2][3] += a2 * cv.w;
            accr[3][0] += a3 * cv.x; accr[3][1] += a3 * cv.y; accr[3][2] += a3 * cv.z; accr[3][3] += a3 * cv.w;
        }
        __syncthreads();
    }
    float4 bbl = *reinterpret_cast<const float4*>(&bl[c0 + tx * 4]);
    float4 bbr = *reinterpret_cast<const float4*>(&br[c0 + tx * 4]);
#pragma unroll
    for (int i = 0; i < 4; i++) {
        int gr = rb + ty * 4 + i;
        if (gr < N_NODES) {
            float4 o;
            o.x = accl[i][0] + bbl.x; o.y = accl[i][1] + bbl.y;
            o.z = accl[i][2] + bbl.z; o.w = accl[i][3] + bbl.w;
            *reinterpret_cast<float4*>(&XL[gr * HC + c0 + tx * 4]) = o;
            o.x = accr[i][0] + bbr.x; o.y = accr[i][1] + bbr.y;
            o.z = accr[i][2] + bbr.z; o.w = accr[i][3] + bbr.w;
            *reinterpret_cast<float4*>(&XR[gr * HC + c0 + tx * 4]) = o;
        }
    }
}

// ---------------- Fused GAT: 2 edges/wave, float4 lanes, 4 chains in flight ----------------
// Lane l: half = l>>5 picks the even/odd edge of a pair; cb = l&31 covers
// channels [4cb,4cb+4); head = cb>>3 (8-lane groups). Scores in log2 domain.

__device__ __forceinline__ float score4(float4 xl, float4 xr, float4 a) {
    float hx = xl.x + xr.x, hy = xl.y + xr.y, hz = xl.z + xr.z, hw = xl.w + xr.w;
    hx = fmaxf(hx, NEG_SLOPE * hx);
    hy = fmaxf(hy, NEG_SLOPE * hy);
    hz = fmaxf(hz, NEG_SLOPE * hz);
    hw = fmaxf(hw, NEG_SLOPE * hw);
    float c = ((a.x * hx + a.y * hy) + (a.z * hz + a.w * hw));
    c += __shfl_xor(c, 1);
    c += __shfl_xor(c, 2);
    c += __shfl_xor(c, 4);     // 8-lane head group holds e_h * log2e
    return c;
}

__device__ __forceinline__ void upd4(float c, float4 xl, float& m, float& z, float4& acc) {
    if (__any(c > m)) {
        float nm = fmaxf(m, c);
        float s = exp2f(m - nm);
        float w = exp2f(c - nm);
        z = z * s + w;
        acc.x = acc.x * s + w * xl.x;
        acc.y = acc.y * s + w * xl.y;
        acc.z = acc.z * s + w * xl.z;
        acc.w = acc.w * s + w * xl.w;
        m = nm;
    } else {
        float w = exp2f(c - m);
        z += w;
        acc.x += w * xl.x;
        acc.y += w * xl.y;
        acc.z += w * xl.z;
        acc.w += w * xl.w;
    }
}

__global__ __launch_bounds__(256) void gat_fused_kernel(const float* __restrict__ XL,
    const float* __restrict__ XR, const float* __restrict__ att,
    const int* __restrict__ rowStart, const int* __restrict__ srcOff,
    const float* __restrict__ bvec, float* __restrict__ out, int applyElu) {
    int wv = threadIdx.x >> 6;
    int l = threadIdx.x & 63;
    int half = l >> 5;
    int cb = l & 31;
    int n = blockIdx.x * 4 + wv;
    if (n >= N_NODES) return;
    int s0 = rowStart[n], s1 = rowStart[n + 1];

    float4 xr4 = *reinterpret_cast<const float4*>(&XR[n * HC + 4 * cb]);
    float4 a4  = *reinterpret_cast<const float4*>(&att[4 * cb]);
    a4.x *= LOG2E; a4.y *= LOG2E; a4.z *= LOG2E; a4.w *= LOG2E;
    const char* XLb = reinterpret_cast<const char*>(XL);
    int lo = 16 * cb;

    float m = NEGBIG, z = 0.f;
    float4 acc = make_float4(0.f, 0.f, 0.f, 0.f);

    int p = s0;
    // 8 edges per iteration: 4 independent load+score chains, then 4 updates
    for (; p + 8 <= s1; p += 8) {
        int oA = srcOff[p     + half];
        int oB = srcOff[p + 2 + half];
        int oC = srcOff[p + 4 + half];
        int oD = srcOff[p + 6 + half];
        float4 xlA = *reinterpret_cast<const float4*>(XLb + (size_t)(oA + lo));
        float4 xlB = *reinterpret_cast<const float4*>(XLb + (size_t)(oB + lo));
        float4 xlC = *reinterpret_cast<const float4*>(XLb + (size_t)(oC + lo));
        float4 xlD = *reinterpret_cast<const float4*>(XLb + (size_t)(oD + lo));
        float cA = score4(xlA, xr4, a4);
        float cB = score4(xlB, xr4, a4);
        float cC = score4(xlC, xr4, a4);
        float cD = score4(xlD, xr4, a4);
        upd4(cA, xlA, m, z, acc);
        upd4(cB, xlB, m, z, acc);
        upd4(cC, xlC, m, z, acc);
        upd4(cD, xlD, m, z, acc);
    }
    for (; p + 2 <= s1; p += 2) {
        int o = srcOff[p + half];
        float4 xl4 = *reinterpret_cast<const float4*>(XLb + (size_t)(o + lo));
        float c = score4(xl4, xr4, a4);
        upd4(c, xl4, m, z, acc);
    }
    if (p < s1) {                               // odd tail: half 1 masked
        int o = srcOff[p];
        float4 xl4 = *reinterpret_cast<const float4*>(XLb + (size_t)(o + lo));
        float c = score4(xl4, xr4, a4);
        if (half) c = NEGBIG;                   // finite poison: killed at combine
        upd4(c, xl4, m, z, acc);
    }

    // merge the two half-wave softmax states (exact rescale combine)
    float mo = __shfl_xor(m, 32);
    float zo = __shfl_xor(z, 32);
    float aox = __shfl_xor(acc.x, 32);
    float aoy = __shfl_xor(acc.y, 32);
    float aoz = __shfl_xor(acc.z, 32);
    float aow = __shfl_xor(acc.w, 32);
    float nm = fmaxf(m, mo);
    float s  = exp2f(m - nm);
    float so = exp2f(mo - nm);
    z = z * s + zo * so;
    acc.x = acc.x * s + aox * so;
    acc.y = acc.y * s + aoy * so;
    acc.z = acc.z * s + aoz * so;
    acc.w = acc.w * s + aow * so;

    if (half == 0) {
        float zinv = 1.f / z;
        float4 b4 = *reinterpret_cast<const float4*>(&bvec[4 * cb]);
        float4 o4;
        o4.x = acc.x * zinv + b4.x;
        o4.y = acc.y * zinv + b4.y;
        o4.z = acc.z * zinv + b4.z;
        o4.w = acc.w * zinv + b4.w;
        if (applyElu) {
            o4.x = o4.x > 0.f ? o4.x : (__expf(o4.x) - 1.f);
            o4.y = o4.y > 0.f ? o4.y : (__expf(o4.y) - 1.f);
            o4.z = o4.z > 0.f ? o4.z : (__expf(o4.z) - 1.f);
            o4.w = o4.w > 0.f ? o4.w : (__expf(o4.w) - 1.f);
        }
        *reinterpret_cast<float4*>(&out[n * HC + 4 * cb]) = o4;
    }
}

// ---------------- launch ----------------

extern "C" void kernel_launch(void* const* d_in, const int* in_sizes, int n_in,
                              void* d_out, int out_size, void* d_ws, size_t ws_size,
                              hipStream_t stream) {
    const float* x = (const float*)d_in[0];
    const int* ei = (const int*)d_in[1];
    const int* srcArr = ei;
    const int* dstArr = ei + N_EDGES;

    char* ws = (char*)d_ws;
    size_t off = 0;
    auto alloc = [&](size_t bytes) -> void* {
        void* p = ws + off;
        off = (off + bytes + 511) & ~(size_t)511;
        return p;
    };
    float* P       = (float*)alloc((size_t)N_NODES * HC * 4);
    float* XL      = (float*)alloc((size_t)N_NODES * HC * 4);
    float* XR      = (float*)alloc((size_t)N_NODES * HC * 4);
    int* deg       = (int*)alloc((size_t)N_NODES * 4);
    int* rowStart  = (int*)alloc((size_t)(N_NODES + 1) * 4);
    int* blockSum  = (int*)alloc(64 * 4);
    int* blockOff  = (int*)alloc(64 * 4);
    int* bucketCur = (int*)alloc((size_t)NBUCKETS * 4);
    int* E         = (int*)alloc((size_t)ETOT * 4);
    int* srcOff    = (int*)alloc((size_t)ETOT * 4);

    const int NSCAN = (N_NODES + 1023) / 1024;   // 49

    hipMemsetAsync(deg, 0, (size_t)N_NODES * 4, stream);
    hist_kernel<<<(ETOT + 255) / 256, 256, 0, stream>>>(dstArr, deg);
    scanA_kernel<<<NSCAN, 1024, 0, stream>>>(deg, rowStart, blockSum);
    scanB_kernel<<<1, 64, 0, stream>>>(blockSum, blockOff, NSCAN);
    scanC_kernel<<<NSCAN, 1024, 0, stream>>>(rowStart, blockOff);
    init_cursor_kernel<<<(NBUCKETS + 255) / 256, 256, 0, stream>>>(rowStart, bucketCur);
    chunk_scatter_kernel<<<NCHUNK, 256, 0, stream>>>(srcArr, dstArr, bucketCur, E);
    csr_scatter_kernel<<<NBUCKETS, 256, 0, stream>>>(E, rowStart, srcOff);

    for (int lyr = 0; lyr < 3; lyr++) {
        const float* xin = (lyr == 0) ? x : P;
        float* xout = (lyr == 2) ? (float*)d_out : P;
        const float* Wl  = (const float*)d_in[2 + 6 * lyr + 0];
        const float* bl  = (const float*)d_in[2 + 6 * lyr + 1];
        const float* Wr  = (const float*)d_in[2 + 6 * lyr + 2];
        const float* br  = (const float*)d_in[2 + 6 * lyr + 3];
        const float* att = (const float*)d_in[2 + 6 * lyr + 4];
        const float* bb  = (const float*)d_in[2 + 6 * lyr + 5];

        dim3 ggrid((N_NODES + 63) / 64, 2);
        gemm_kernel<<<ggrid, 256, 0, stream>>>(xin, Wl, bl, Wr, br, XL, XR);

        int nb = (N_NODES + 3) / 4;
        gat_fused_kernel<<<nb, 256, 0, stream>>>(XL, XR, att, rowStart, srcOff, bb, xout, lyr < 2 ? 1 : 0);
    }
}

// Round 7
// 605.387 us; speedup vs baseline: 1.1128x; 1.0243x over previous
//
#include <hip/hip_runtime.h>
#include <math.h>

#define N_NODES 50000
#define N_EDGES 1600000
#define ETOT (N_EDGES + N_NODES)
#define HC 128
#define HEADS 4
#define HID 32
#define NEG_SLOPE 0.2f
#define NPB 32                               // nodes per bucket (aligned)
#define NBUCKETS ((N_NODES + NPB - 1) / NPB) // 1563
#define CHUNK 8192
#define NCHUNK ((ETOT + CHUNK - 1) / CHUNK)  // 202
#define LOG2E 1.4426950408889634f
#define NEGBIG (-1e30f)

// ---------------- CSR build ----------------

__global__ __launch_bounds__(256) void hist_kernel(const int* __restrict__ dstArr, int* __restrict__ deg) {
    int i = blockIdx.x * 256 + threadIdx.x;
    if (i >= ETOT) return;
    int d = (i < N_EDGES) ? dstArr[i] : (i - N_EDGES);
    atomicAdd(&deg[d], 1);
}

__global__ __launch_bounds__(1024) void scanA_kernel(const int* __restrict__ deg,
                                                     int* __restrict__ rowStart, int* __restrict__ blockSum) {
    __shared__ int buf[1024];
    int i = blockIdx.x * 1024 + threadIdx.x;
    int v = (i < N_NODES) ? deg[i] : 0;
    buf[threadIdx.x] = v;
    __syncthreads();
    for (int off = 1; off < 1024; off <<= 1) {
        int t = (threadIdx.x >= off) ? buf[threadIdx.x - off] : 0;
        __syncthreads();
        buf[threadIdx.x] += t;
        __syncthreads();
    }
    if (i < N_NODES) rowStart[i] = buf[threadIdx.x] - v;   // exclusive, pre-offset
    if (threadIdx.x == 1023) blockSum[blockIdx.x] = buf[1023];
}

__global__ void scanB_kernel(const int* __restrict__ blockSum, int* __restrict__ blockOff, int nb) {
    if (threadIdx.x == 0 && blockIdx.x == 0) {
        int acc = 0;
        for (int j = 0; j < nb; j++) { blockOff[j] = acc; acc += blockSum[j]; }
    }
}

__global__ __launch_bounds__(1024) void scanC_kernel(int* __restrict__ rowStart, const int* __restrict__ blockOff) {
    int i = blockIdx.x * 1024 + threadIdx.x;
    if (i < N_NODES) rowStart[i] += blockOff[blockIdx.x];
    if (i == 0) rowStart[N_NODES] = ETOT;   // sentinel
}

__global__ __launch_bounds__(256) void init_cursor_kernel(const int* __restrict__ rowStart, int* __restrict__ bucketCursor) {
    int b = blockIdx.x * 256 + threadIdx.x;
    if (b < NBUCKETS) bucketCursor[b] = rowStart[b * NPB];
}

// Pass 1: chunked counting-sort scatter to bucket granularity.
__global__ __launch_bounds__(256) void chunk_scatter_kernel(const int* __restrict__ srcArr, const int* __restrict__ dstArr,
                                                            int* __restrict__ bucketCursor, int* __restrict__ E) {
    __shared__ int hist[NBUCKETS];   // then reused as running cursor
    int c0 = blockIdx.x * CHUNK;
    int c1 = min(c0 + CHUNK, ETOT);
    for (int b = threadIdx.x; b < NBUCKETS; b += 256) hist[b] = 0;
    __syncthreads();

    int myP[CHUNK / 256];   // packed src | (d<<16)
    int cnt = 0;
    for (int i = c0 + threadIdx.x; i < c1; i += 256) {
        int s, d;
        if (i < N_EDGES) { s = srcArr[i]; d = dstArr[i]; }
        else             { s = i - N_EDGES; d = s; }
        myP[cnt] = s | (d << 16);
        cnt++;
        atomicAdd(&hist[d >> 5], 1);
    }
    __syncthreads();
    for (int b = threadIdx.x; b < NBUCKETS; b += 256) {
        int h = hist[b];
        hist[b] = (h > 0) ? atomicAdd(&bucketCursor[b], h) : 0;
    }
    __syncthreads();
    for (int k = 0; k < cnt; k++) {
        int pe = myP[k];
        int pos = atomicAdd(&hist[((unsigned)pe) >> 21], 1);   // bucket = d>>5
        E[pos] = pe;
    }
}

// Pass 2: one block per bucket; emits BYTE offsets src*512 into srcOff
__global__ __launch_bounds__(256) void csr_scatter_kernel(const int* __restrict__ E, const int* __restrict__ rowStart,
                                                          int* __restrict__ srcOff) {
    __shared__ int lcur[NPB];
    int b = blockIdx.x;
    int n0 = b * NPB;
    int nend = min(n0 + NPB, N_NODES);
    if (threadIdx.x < nend - n0) lcur[threadIdx.x] = rowStart[n0 + threadIdx.x];
    __syncthreads();
    int e0 = rowStart[n0];
    int e1 = rowStart[nend];
    for (int i = e0 + threadIdx.x; i < e1; i += 256) {
        int pe = E[i];
        int pos = atomicAdd(&lcur[(pe >> 16) & (NPB - 1)], 1);
        srcOff[pos] = (pe & 0xFFFF) << 9;     // byte offset into XL (row = 512 B)
    }
}

// ---------------- GEMM: XL = x@Wl + bl, XR = x@Wr + br ----------------
// grid = (ceil(N/64), 4). blockIdx.y selects 64-col tile of [Wl | Wr] (256 cols).
// (r4 form: 17 KB LDS -> better blocks/CU than the shared-A variant.)

__global__ __launch_bounds__(256) void gemm_kernel(const float* __restrict__ x,
    const float* __restrict__ Wl, const float* __restrict__ bl,
    const float* __restrict__ Wr, const float* __restrict__ br,
    float* __restrict__ XL, float* __restrict__ XR) {
    __shared__ float As[64][68];
    __shared__ float Bs[64][64];
    int t = threadIdx.x;
    int rb = blockIdx.x * 64;
    int cb = blockIdx.y * 64;
    const float* W; const float* bias; float* out; int c0;
    if (cb < HC) { W = Wl; bias = bl; out = XL; c0 = cb; }
    else         { W = Wr; bias = br; out = XR; c0 = cb - HC; }
    int tx = t & 15, ty = t >> 4;
    float acc[4][4];
#pragma unroll
    for (int i = 0; i < 4; i++)
#pragma unroll
        for (int j = 0; j < 4; j++) acc[i][j] = 0.f;

    for (int kt = 0; kt < 2; kt++) {
#pragma unroll
        for (int it = 0; it < 4; it++) {
            int idx = it * 256 + t;
            int r = idx >> 4, f = idx & 15;
            int gr = rb + r;
            float4 v = make_float4(0.f, 0.f, 0.f, 0.f);
            if (gr < N_NODES) v = *reinterpret_cast<const float4*>(&x[gr * HC + kt * 64 + f * 4]);
            *reinterpret_cast<float4*>(&As[r][f * 4]) = v;
        }
#pragma unroll
        for (int it = 0; it < 4; it++) {
            int idx = it * 256 + t;
            int k = idx >> 4, f = idx & 15;
            float4 v = *reinterpret_cast<const float4*>(&W[(kt * 64 + k) * HC + c0 + f * 4]);
            *reinterpret_cast<float4*>(&Bs[k][f * 4]) = v;
        }
        __syncthreads();
#pragma unroll
        for (int k = 0; k < 64; k++) {
            float a0 = As[ty * 4 + 0][k];
            float a1 = As[ty * 4 + 1][k];
            float a2 = As[ty * 4 + 2][k];
            float a3 = As[ty * 4 + 3][k];
            float4 bv = *reinterpret_cast<const float4*>(&Bs[k][tx * 4]);
            acc[0][0] += a0 * bv.x; acc[0][1] += a0 * bv.y; acc[0][2] += a0 * bv.z; acc[0][3] += a0 * bv.w;
            acc[1][0] += a1 * bv.x; acc[1][1] += a1 * bv.y; acc[1][2] += a1 * bv.z; acc[1][3] += a1 * bv.w;
            acc[2][0] += a2 * bv.x; acc[2][1] += a2 * bv.y; acc[2][2] += a2 * bv.z; acc[2][3] += a2 * bv.w;
            acc[3][0] += a3 * bv.x; acc[3][1] += a3 * bv.y; acc[3][2] += a3 * bv.z; acc[3][3] += a3 * bv.w;
        }
        __syncthreads();
    }
    float4 bb = *reinterpret_cast<const float4*>(&bias[c0 + tx * 4]);
#pragma unroll
    for (int i = 0; i < 4; i++) {
        int gr = rb + ty * 4 + i;
        if (gr < N_NODES) {
            float4 o;
            o.x = acc[i][0] + bb.x; o.y = acc[i][1] + bb.y;
            o.z = acc[i][2] + bb.z; o.w = acc[i][3] + bb.w;
            *reinterpret_cast<float4*>(&out[gr * HC + c0 + tx * 4]) = o;
        }
    }
}

// ---------------- Fused GAT: 2 edges/wave, float4 lanes, direct-exp softmax ----------------
// Lane l: half = l>>5 picks even/odd edge of a pair; cb = l&31 covers channels
// [4cb,4cb+4); head = cb>>3 (8-lane groups). Scores in log2 domain (att pre-scaled).
// No running max: scores are O(10) for this data; clamp at 120 (exp2 overflow
// insurance). z-normalization makes it mathematically identical to max-shifted.

__device__ __forceinline__ float score4(float4 xl, float4 xr, float4 a) {
    float hx = xl.x + xr.x, hy = xl.y + xr.y, hz = xl.z + xr.z, hw = xl.w + xr.w;
    hx = fmaxf(hx, NEG_SLOPE * hx);
    hy = fmaxf(hy, NEG_SLOPE * hy);
    hz = fmaxf(hz, NEG_SLOPE * hz);
    hw = fmaxf(hw, NEG_SLOPE * hw);
    float c = ((a.x * hx + a.y * hy) + (a.z * hz + a.w * hw));
    c += __shfl_xor(c, 1);
    c += __shfl_xor(c, 2);
    c += __shfl_xor(c, 4);     // 8-lane head group holds e_h * log2e
    return fminf(c, 120.f);    // overflow insurance
}

__device__ __forceinline__ void upd4(float c, float4 xl, float& z, float4& acc) {
    float w = exp2f(c);
    z += w;
    acc.x += w * xl.x;
    acc.y += w * xl.y;
    acc.z += w * xl.z;
    acc.w += w * xl.w;
}

__global__ __launch_bounds__(256) void gat_fused_kernel(const float* __restrict__ XL,
    const float* __restrict__ XR, const float* __restrict__ att,
    const int* __restrict__ rowStart, const int* __restrict__ srcOff,
    const float* __restrict__ bvec, float* __restrict__ out, int applyElu) {
    int wv = threadIdx.x >> 6;
    int l = threadIdx.x & 63;
    int half = l >> 5;
    int cb = l & 31;
    int n = blockIdx.x * 4 + wv;
    if (n >= N_NODES) return;
    int s0 = rowStart[n], s1 = rowStart[n + 1];

    float4 xr4 = *reinterpret_cast<const float4*>(&XR[n * HC + 4 * cb]);
    float4 a4  = *reinterpret_cast<const float4*>(&att[4 * cb]);
    a4.x *= LOG2E; a4.y *= LOG2E; a4.z *= LOG2E; a4.w *= LOG2E;
    const char* XLb = reinterpret_cast<const char*>(XL) + 16 * cb;  // lane channel base folded in

    float z = 0.f;
    float4 acc = make_float4(0.f, 0.f, 0.f, 0.f);

    int p = s0;
    // 8 edges per iteration: 4 independent load+score chains, then 4 independent accums
    for (; p + 8 <= s1; p += 8) {
        int oA = srcOff[p     + half];
        int oB = srcOff[p + 2 + half];
        int oC = srcOff[p + 4 + half];
        int oD = srcOff[p + 6 + half];
        float4 xlA = *reinterpret_cast<const float4*>(XLb + (size_t)oA);
        float4 xlB = *reinterpret_cast<const float4*>(XLb + (size_t)oB);
        float4 xlC = *reinterpret_cast<const float4*>(XLb + (size_t)oC);
        float4 xlD = *reinterpret_cast<const float4*>(XLb + (size_t)oD);
        float cA = score4(xlA, xr4, a4);
        float cB = score4(xlB, xr4, a4);
        float cC = score4(xlC, xr4, a4);
        float cD = score4(xlD, xr4, a4);
        upd4(cA, xlA, z, acc);
        upd4(cB, xlB, z, acc);
        upd4(cC, xlC, z, acc);
        upd4(cD, xlD, z, acc);
    }
    for (; p + 2 <= s1; p += 2) {
        int o = srcOff[p + half];
        float4 xl4 = *reinterpret_cast<const float4*>(XLb + (size_t)o);
        float c = score4(xl4, xr4, a4);
        upd4(c, xl4, z, acc);
    }
    if (p < s1) {                               // odd tail: half 1 contributes w=0
        int o = srcOff[p];
        float4 xl4 = *reinterpret_cast<const float4*>(XLb + (size_t)o);
        float c = score4(xl4, xr4, a4);
        if (half) c = NEGBIG;                   // exp2(-1e30) == 0
        upd4(c, xl4, z, acc);
    }

    // merge the two half-wave partial sums
    z     += __shfl_xor(z, 32);
    acc.x += __shfl_xor(acc.x, 32);
    acc.y += __shfl_xor(acc.y, 32);
    acc.z += __shfl_xor(acc.z, 32);
    acc.w += __shfl_xor(acc.w, 32);

    if (half == 0) {
        float zinv = 1.f / z;
        float4 b4 = *reinterpret_cast<const float4*>(&bvec[4 * cb]);
        float4 o4;
        o4.x = acc.x * zinv + b4.x;
        o4.y = acc.y * zinv + b4.y;
        o4.z = acc.z * zinv + b4.z;
        o4.w = acc.w * zinv + b4.w;
        if (applyElu) {
            o4.x = o4.x > 0.f ? o4.x : (__expf(o4.x) - 1.f);
            o4.y = o4.y > 0.f ? o4.y : (__expf(o4.y) - 1.f);
            o4.z = o4.z > 0.f ? o4.z : (__expf(o4.z) - 1.f);
            o4.w = o4.w > 0.f ? o4.w : (__expf(o4.w) - 1.f);
        }
        *reinterpret_cast<float4*>(&out[n * HC + 4 * cb]) = o4;
    }
}

// ---------------- launch ----------------

extern "C" void kernel_launch(void* const* d_in, const int* in_sizes, int n_in,
                              void* d_out, int out_size, void* d_ws, size_t ws_size,
                              hipStream_t stream) {
    const float* x = (const float*)d_in[0];
    const int* ei = (const int*)d_in[1];
    const int* srcArr = ei;
    const int* dstArr = ei + N_EDGES;

    char* ws = (char*)d_ws;
    size_t off = 0;
    auto alloc = [&](size_t bytes) -> void* {
        void* p = ws + off;
        off = (off + bytes + 511) & ~(size_t)511;
        return p;
    };
    float* P       = (float*)alloc((size_t)N_NODES * HC * 4);
    float* XL      = (float*)alloc((size_t)N_NODES * HC * 4);
    float* XR      = (float*)alloc((size_t)N_NODES * HC * 4);
    int* deg       = (int*)alloc((size_t)N_NODES * 4);
    int* rowStart  = (int*)alloc((size_t)(N_NODES + 1) * 4);
    int* blockSum  = (int*)alloc(64 * 4);
    int* blockOff  = (int*)alloc(64 * 4);
    int* bucketCur = (int*)alloc((size_t)NBUCKETS * 4);
    int* E         = (int*)alloc((size_t)ETOT * 4);
    int* srcOff    = (int*)alloc((size_t)ETOT * 4);

    const int NSCAN = (N_NODES + 1023) / 1024;   // 49

    hipMemsetAsync(deg, 0, (size_t)N_NODES * 4, stream);
    hist_kernel<<<(ETOT + 255) / 256, 256, 0, stream>>>(dstArr, deg);
    scanA_kernel<<<NSCAN, 1024, 0, stream>>>(deg, rowStart, blockSum);
    scanB_kernel<<<1, 64, 0, stream>>>(blockSum, blockOff, NSCAN);
    scanC_kernel<<<NSCAN, 1024, 0, stream>>>(rowStart, blockOff);
    init_cursor_kernel<<<(NBUCKETS + 255) / 256, 256, 0, stream>>>(rowStart, bucketCur);
    chunk_scatter_kernel<<<NCHUNK, 256, 0, stream>>>(srcArr, dstArr, bucketCur, E);
    csr_scatter_kernel<<<NBUCKETS, 256, 0, stream>>>(E, rowStart, srcOff);

    for (int lyr = 0; lyr < 3; lyr++) {
        const float* xin = (lyr == 0) ? x : P;
        float* xout = (lyr == 2) ? (float*)d_out : P;
        const float* Wl  = (const float*)d_in[2 + 6 * lyr + 0];
        const float* bl  = (const float*)d_in[2 + 6 * lyr + 1];
        const float* Wr  = (const float*)d_in[2 + 6 * lyr + 2];
        const float* br  = (const float*)d_in[2 + 6 * lyr + 3];
        const float* att = (const float*)d_in[2 + 6 * lyr + 4];
        const float* bb  = (const float*)d_in[2 + 6 * lyr + 5];

        dim3 ggrid((N_NODES + 63) / 64, 4);
        gemm_kernel<<<ggrid, 256, 0, stream>>>(xin, Wl, bl, Wr, br, XL, XR);

        int nb = (N_NODES + 3) / 4;
        gat_fused_kernel<<<nb, 256, 0, stream>>>(XL, XR, att, rowStart, srcOff, bb, xout, lyr < 2 ? 1 : 0);
    }
}

// Round 8
// 601.226 us; speedup vs baseline: 1.1205x; 1.0069x over previous
//
#include <hip/hip_runtime.h>
#include <math.h>

#define N_NODES 50000
#define N_EDGES 1600000
#define ETOT (N_EDGES + N_NODES)
#define HC 128
#define HEADS 4
#define HID 32
#define NEG_SLOPE 0.2f
#define NPB 32                               // nodes per bucket (aligned)
#define NBUCKETS ((N_NODES + NPB - 1) / NPB) // 1563
#define CHUNK 8192
#define NCHUNK ((ETOT + CHUNK - 1) / CHUNK)  // 202
#define LOG2E 1.4426950408889634f
#define NEGBIG (-1e30f)

// ---------------- CSR build ----------------

__global__ __launch_bounds__(256) void hist_kernel(const int* __restrict__ dstArr, int* __restrict__ deg) {
    int i = blockIdx.x * 256 + threadIdx.x;
    if (i >= ETOT) return;
    int d = (i < N_EDGES) ? dstArr[i] : (i - N_EDGES);
    atomicAdd(&deg[d], 1);
}

__global__ __launch_bounds__(1024) void scanA_kernel(const int* __restrict__ deg,
                                                     int* __restrict__ rowStart, int* __restrict__ blockSum) {
    __shared__ int buf[1024];
    int i = blockIdx.x * 1024 + threadIdx.x;
    int v = (i < N_NODES) ? deg[i] : 0;
    buf[threadIdx.x] = v;
    __syncthreads();
    for (int off = 1; off < 1024; off <<= 1) {
        int t = (threadIdx.x >= off) ? buf[threadIdx.x - off] : 0;
        __syncthreads();
        buf[threadIdx.x] += t;
        __syncthreads();
    }
    if (i < N_NODES) rowStart[i] = buf[threadIdx.x] - v;   // exclusive, pre-offset
    if (threadIdx.x == 1023) blockSum[blockIdx.x] = buf[1023];
}

__global__ void scanB_kernel(const int* __restrict__ blockSum, int* __restrict__ blockOff, int nb) {
    if (threadIdx.x == 0 && blockIdx.x == 0) {
        int acc = 0;
        for (int j = 0; j < nb; j++) { blockOff[j] = acc; acc += blockSum[j]; }
    }
}

__global__ __launch_bounds__(1024) void scanC_kernel(int* __restrict__ rowStart, const int* __restrict__ blockOff) {
    int i = blockIdx.x * 1024 + threadIdx.x;
    if (i < N_NODES) rowStart[i] += blockOff[blockIdx.x];
    if (i == 0) rowStart[N_NODES] = ETOT;   // sentinel
}

__global__ __launch_bounds__(256) void init_cursor_kernel(const int* __restrict__ rowStart, int* __restrict__ bucketCursor) {
    int b = blockIdx.x * 256 + threadIdx.x;
    if (b < NBUCKETS) bucketCursor[b] = rowStart[b * NPB];
}

// Pass 1: chunked counting-sort scatter to bucket granularity.
__global__ __launch_bounds__(256) void chunk_scatter_kernel(const int* __restrict__ srcArr, const int* __restrict__ dstArr,
                                                            int* __restrict__ bucketCursor, int* __restrict__ E) {
    __shared__ int hist[NBUCKETS];   // then reused as running cursor
    int c0 = blockIdx.x * CHUNK;
    int c1 = min(c0 + CHUNK, ETOT);
    for (int b = threadIdx.x; b < NBUCKETS; b += 256) hist[b] = 0;
    __syncthreads();

    int myP[CHUNK / 256];   // packed src | (d<<16)
    int cnt = 0;
    for (int i = c0 + threadIdx.x; i < c1; i += 256) {
        int s, d;
        if (i < N_EDGES) { s = srcArr[i]; d = dstArr[i]; }
        else             { s = i - N_EDGES; d = s; }
        myP[cnt] = s | (d << 16);
        cnt++;
        atomicAdd(&hist[d >> 5], 1);
    }
    __syncthreads();
    for (int b = threadIdx.x; b < NBUCKETS; b += 256) {
        int h = hist[b];
        hist[b] = (h > 0) ? atomicAdd(&bucketCursor[b], h) : 0;
    }
    __syncthreads();
    for (int k = 0; k < cnt; k++) {
        int pe = myP[k];
        int pos = atomicAdd(&hist[((unsigned)pe) >> 21], 1);   // bucket = d>>5
        E[pos] = pe;
    }
}

// Pass 2: one block per bucket; emits BYTE offsets src*512 into srcOff
__global__ __launch_bounds__(256) void csr_scatter_kernel(const int* __restrict__ E, const int* __restrict__ rowStart,
                                                          int* __restrict__ srcOff) {
    __shared__ int lcur[NPB];
    int b = blockIdx.x;
    int n0 = b * NPB;
    int nend = min(n0 + NPB, N_NODES);
    if (threadIdx.x < nend - n0) lcur[threadIdx.x] = rowStart[n0 + threadIdx.x];
    __syncthreads();
    int e0 = rowStart[n0];
    int e1 = rowStart[nend];
    for (int i = e0 + threadIdx.x; i < e1; i += 256) {
        int pe = E[i];
        int pos = atomicAdd(&lcur[(pe >> 16) & (NPB - 1)], 1);
        srcOff[pos] = (pe & 0xFFFF) << 9;     // byte offset into XL (row = 512 B)
    }
}

// ---------------- GEMM: XL = x@Wl + bl, XR = x@Wr + br ----------------
// grid = (ceil(N/64), 4). blockIdx.y selects 64-col tile of [Wl | Wr] (256 cols).

__global__ __launch_bounds__(256) void gemm_kernel(const float* __restrict__ x,
    const float* __restrict__ Wl, const float* __restrict__ bl,
    const float* __restrict__ Wr, const float* __restrict__ br,
    float* __restrict__ XL, float* __restrict__ XR) {
    __shared__ float As[64][68];
    __shared__ float Bs[64][64];
    int t = threadIdx.x;
    int rb = blockIdx.x * 64;
    int cb = blockIdx.y * 64;
    const float* W; const float* bias; float* out; int c0;
    if (cb < HC) { W = Wl; bias = bl; out = XL; c0 = cb; }
    else         { W = Wr; bias = br; out = XR; c0 = cb - HC; }
    int tx = t & 15, ty = t >> 4;
    float acc[4][4];
#pragma unroll
    for (int i = 0; i < 4; i++)
#pragma unroll
        for (int j = 0; j < 4; j++) acc[i][j] = 0.f;

    for (int kt = 0; kt < 2; kt++) {
#pragma unroll
        for (int it = 0; it < 4; it++) {
            int idx = it * 256 + t;
            int r = idx >> 4, f = idx & 15;
            int gr = rb + r;
            float4 v = make_float4(0.f, 0.f, 0.f, 0.f);
            if (gr < N_NODES) v = *reinterpret_cast<const float4*>(&x[gr * HC + kt * 64 + f * 4]);
            *reinterpret_cast<float4*>(&As[r][f * 4]) = v;
        }
#pragma unroll
        for (int it = 0; it < 4; it++) {
            int idx = it * 256 + t;
            int k = idx >> 4, f = idx & 15;
            float4 v = *reinterpret_cast<const float4*>(&W[(kt * 64 + k) * HC + c0 + f * 4]);
            *reinterpret_cast<float4*>(&Bs[k][f * 4]) = v;
        }
        __syncthreads();
#pragma unroll
        for (int k = 0; k < 64; k++) {
            float a0 = As[ty * 4 + 0][k];
            float a1 = As[ty * 4 + 1][k];
            float a2 = As[ty * 4 + 2][k];
            float a3 = As[ty * 4 + 3][k];
            float4 bv = *reinterpret_cast<const float4*>(&Bs[k][tx * 4]);
            acc[0][0] += a0 * bv.x; acc[0][1] += a0 * bv.y; acc[0][2] += a0 * bv.z; acc[0][3] += a0 * bv.w;
            acc[1][0] += a1 * bv.x; acc[1][1] += a1 * bv.y; acc[1][2] += a1 * bv.z; acc[1][3] += a1 * bv.w;
            acc[2][0] += a2 * bv.x; acc[2][1] += a2 * bv.y; acc[2][2] += a2 * bv.z; acc[2][3] += a2 * bv.w;
            acc[3][0] += a3 * bv.x; acc[3][1] += a3 * bv.y; acc[3][2] += a3 * bv.z; acc[3][3] += a3 * bv.w;
        }
        __syncthreads();
    }
    float4 bb = *reinterpret_cast<const float4*>(&bias[c0 + tx * 4]);
#pragma unroll
    for (int i = 0; i < 4; i++) {
        int gr = rb + ty * 4 + i;
        if (gr < N_NODES) {
            float4 o;
            o.x = acc[i][0] + bb.x; o.y = acc[i][1] + bb.y;
            o.z = acc[i][2] + bb.z; o.w = acc[i][3] + bb.w;
            *reinterpret_cast<float4*>(&out[gr * HC + c0 + tx * 4]) = o;
        }
    }
}

// ---------------- Fused GAT: 2 edges/wave, float4 lanes, direct-exp, 8 chains ----------------
// Lane l: half = l>>5 picks even/odd edge of a pair; cb = l&31 covers channels
// [4cb,4cb+4); head = cb>>3 (8-lane groups). Scores in log2 domain (att pre-scaled).

__device__ __forceinline__ float score4(float4 xl, float4 xr, float4 a) {
    float hx = xl.x + xr.x, hy = xl.y + xr.y, hz = xl.z + xr.z, hw = xl.w + xr.w;
    hx = fmaxf(hx, NEG_SLOPE * hx);
    hy = fmaxf(hy, NEG_SLOPE * hy);
    hz = fmaxf(hz, NEG_SLOPE * hz);
    hw = fmaxf(hw, NEG_SLOPE * hw);
    float c = ((a.x * hx + a.y * hy) + (a.z * hz + a.w * hw));
    c += __shfl_xor(c, 1);
    c += __shfl_xor(c, 2);
    c += __shfl_xor(c, 4);     // 8-lane head group holds e_h * log2e
    return fminf(c, 120.f);    // overflow insurance
}

__device__ __forceinline__ void upd4(float c, float4 xl, float& z, float4& acc) {
    float w = exp2f(c);
    z += w;
    acc.x += w * xl.x;
    acc.y += w * xl.y;
    acc.z += w * xl.z;
    acc.w += w * xl.w;
}

__global__ __launch_bounds__(256) void gat_fused_kernel(const float* __restrict__ XL,
    const float* __restrict__ XR, const float* __restrict__ att,
    const int* __restrict__ rowStart, const int* __restrict__ srcOff,
    const float* __restrict__ bvec, float* __restrict__ out, int applyElu) {
    int wv = threadIdx.x >> 6;
    int l = threadIdx.x & 63;
    int half = l >> 5;
    int cb = l & 31;
    int n = blockIdx.x * 4 + wv;
    if (n >= N_NODES) return;
    int s0 = rowStart[n], s1 = rowStart[n + 1];

    float4 xr4 = *reinterpret_cast<const float4*>(&XR[n * HC + 4 * cb]);
    float4 a4  = *reinterpret_cast<const float4*>(&att[4 * cb]);
    a4.x *= LOG2E; a4.y *= LOG2E; a4.z *= LOG2E; a4.w *= LOG2E;
    const char* XLb = reinterpret_cast<const char*>(XL) + 16 * cb;  // lane channel base folded in

    float z = 0.f;
    float4 acc = make_float4(0.f, 0.f, 0.f, 0.f);

    int p = s0;
    // 16 edges per iteration: 8 independent load+score chains
    for (; p + 16 <= s1; p += 16) {
        int oA = srcOff[p      + half];
        int oB = srcOff[p + 2  + half];
        int oC = srcOff[p + 4  + half];
        int oD = srcOff[p + 6  + half];
        int oE = srcOff[p + 8  + half];
        int oF = srcOff[p + 10 + half];
        int oG = srcOff[p + 12 + half];
        int oH = srcOff[p + 14 + half];
        float4 xlA = *reinterpret_cast<const float4*>(XLb + (size_t)oA);
        float4 xlB = *reinterpret_cast<const float4*>(XLb + (size_t)oB);
        float4 xlC = *reinterpret_cast<const float4*>(XLb + (size_t)oC);
        float4 xlD = *reinterpret_cast<const float4*>(XLb + (size_t)oD);
        float4 xlE = *reinterpret_cast<const float4*>(XLb + (size_t)oE);
        float4 xlF = *reinterpret_cast<const float4*>(XLb + (size_t)oF);
        float4 xlG = *reinterpret_cast<const float4*>(XLb + (size_t)oG);
        float4 xlH = *reinterpret_cast<const float4*>(XLb + (size_t)oH);
        float cA = score4(xlA, xr4, a4);
        float cB = score4(xlB, xr4, a4);
        float cC = score4(xlC, xr4, a4);
        float cD = score4(xlD, xr4, a4);
        upd4(cA, xlA, z, acc);
        upd4(cB, xlB, z, acc);
        upd4(cC, xlC, z, acc);
        upd4(cD, xlD, z, acc);
        float cE = score4(xlE, xr4, a4);
        float cF = score4(xlF, xr4, a4);
        float cG = score4(xlG, xr4, a4);
        float cH = score4(xlH, xr4, a4);
        upd4(cE, xlE, z, acc);
        upd4(cF, xlF, z, acc);
        upd4(cG, xlG, z, acc);
        upd4(cH, xlH, z, acc);
    }
    for (; p + 8 <= s1; p += 8) {
        int oA = srcOff[p     + half];
        int oB = srcOff[p + 2 + half];
        int oC = srcOff[p + 4 + half];
        int oD = srcOff[p + 6 + half];
        float4 xlA = *reinterpret_cast<const float4*>(XLb + (size_t)oA);
        float4 xlB = *reinterpret_cast<const float4*>(XLb + (size_t)oB);
        float4 xlC = *reinterpret_cast<const float4*>(XLb + (size_t)oC);
        float4 xlD = *reinterpret_cast<const float4*>(XLb + (size_t)oD);
        float cA = score4(xlA, xr4, a4);
        float cB = score4(xlB, xr4, a4);
        float cC = score4(xlC, xr4, a4);
        float cD = score4(xlD, xr4, a4);
        upd4(cA, xlA, z, acc);
        upd4(cB, xlB, z, acc);
        upd4(cC, xlC, z, acc);
        upd4(cD, xlD, z, acc);
    }
    for (; p + 2 <= s1; p += 2) {
        int o = srcOff[p + half];
        float4 xl4 = *reinterpret_cast<const float4*>(XLb + (size_t)o);
        float c = score4(xl4, xr4, a4);
        upd4(c, xl4, z, acc);
    }
    if (p < s1) {                               // odd tail: half 1 contributes w=0
        int o = srcOff[p];
        float4 xl4 = *reinterpret_cast<const float4*>(XLb + (size_t)o);
        float c = score4(xl4, xr4, a4);
        if (half) c = NEGBIG;                   // exp2(-1e30) == 0
        upd4(c, xl4, z, acc);
    }

    // merge the two half-wave partial sums
    z     += __shfl_xor(z, 32);
    acc.x += __shfl_xor(acc.x, 32);
    acc.y += __shfl_xor(acc.y, 32);
    acc.z += __shfl_xor(acc.z, 32);
    acc.w += __shfl_xor(acc.w, 32);

    if (half == 0) {
        float zinv = 1.f / z;
        float4 b4 = *reinterpret_cast<const float4*>(&bvec[4 * cb]);
        float4 o4;
        o4.x = acc.x * zinv + b4.x;
        o4.y = acc.y * zinv + b4.y;
        o4.z = acc.z * zinv + b4.z;
        o4.w = acc.w * zinv + b4.w;
        if (applyElu) {
            o4.x = o4.x > 0.f ? o4.x : (__expf(o4.x) - 1.f);
            o4.y = o4.y > 0.f ? o4.y : (__expf(o4.y) - 1.f);
            o4.z = o4.z > 0.f ? o4.z : (__expf(o4.z) - 1.f);
            o4.w = o4.w > 0.f ? o4.w : (__expf(o4.w) - 1.f);
        }
        *reinterpret_cast<float4*>(&out[n * HC + 4 * cb]) = o4;
    }
}

// ---------------- launch ----------------

extern "C" void kernel_launch(void* const* d_in, const int* in_sizes, int n_in,
                              void* d_out, int out_size, void* d_ws, size_t ws_size,
                              hipStream_t stream) {
    const float* x = (const float*)d_in[0];
    const int* ei = (const int*)d_in[1];
    const int* srcArr = ei;
    const int* dstArr = ei + N_EDGES;

    char* ws = (char*)d_ws;
    size_t off = 0;
    auto alloc = [&](size_t bytes) -> void* {
        void* p = ws + off;
        off = (off + bytes + 511) & ~(size_t)511;
        return p;
    };
    float* P       = (float*)alloc((size_t)N_NODES * HC * 4);
    float* XL      = (float*)alloc((size_t)N_NODES * HC * 4);
    float* XR      = (float*)alloc((size_t)N_NODES * HC * 4);
    int* deg       = (int*)alloc((size_t)N_NODES * 4);
    int* rowStart  = (int*)alloc((size_t)(N_NODES + 1) * 4);
    int* blockSum  = (int*)alloc(64 * 4);
    int* blockOff  = (int*)alloc(64 * 4);
    int* bucketCur = (int*)alloc((size_t)NBUCKETS * 4);
    int* E         = (int*)alloc((size_t)ETOT * 4);
    int* srcOff    = (int*)alloc((size_t)ETOT * 4);

    const int NSCAN = (N_NODES + 1023) / 1024;   // 49

    hipMemsetAsync(deg, 0, (size_t)N_NODES * 4, stream);
    hist_kernel<<<(ETOT + 255) / 256, 256, 0, stream>>>(dstArr, deg);
    scanA_kernel<<<NSCAN, 1024, 0, stream>>>(deg, rowStart, blockSum);
    scanB_kernel<<<1, 64, 0, stream>>>(blockSum, blockOff, NSCAN);
    scanC_kernel<<<NSCAN, 1024, 0, stream>>>(rowStart, blockOff);
    init_cursor_kernel<<<(NBUCKETS + 255) / 256, 256, 0, stream>>>(rowStart, bucketCur);
    chunk_scatter_kernel<<<NCHUNK, 256, 0, stream>>>(srcArr, dstArr, bucketCur, E);
    csr_scatter_kernel<<<NBUCKETS, 256, 0, stream>>>(E, rowStart, srcOff);

    for (int lyr = 0; lyr < 3; lyr++) {
        const float* xin = (lyr == 0) ? x : P;
        float* xout = (lyr == 2) ? (float*)d_out : P;
        const float* Wl  = (const float*)d_in[2 + 6 * lyr + 0];
        const float* bl  = (const float*)d_in[2 + 6 * lyr + 1];
        const float* Wr  = (const float*)d_in[2 + 6 * lyr + 2];
        const float* br  = (const float*)d_in[2 + 6 * lyr + 3];
        const float* att = (const float*)d_in[2 + 6 * lyr + 4];
        const float* bb  = (const float*)d_in[2 + 6 * lyr + 5];

        dim3 ggrid((N_NODES + 63) / 64, 4);
        gemm_kernel<<<ggrid, 256, 0, stream>>>(xin, Wl, bl, Wr, br, XL, XR);

        int nb = (N_NODES + 3) / 4;
        gat_fused_kernel<<<nb, 256, 0, stream>>>(XL, XR, att, rowStart, srcOff, bb, xout, lyr < 2 ? 1 : 0);
    }
}